// Round 9
// baseline (290.584 us; speedup 1.0000x reference)
//
#include <hip/hip_runtime.h>

#define B_TOT 4096
#define S_LEN 1024
#define HID 30
#define SKIP 16
#define HLEN (S_LEN - SKIP)   // 1008
#define WARM 32               // h2 warm-up steps for chunks >= 1

typedef float f32x4 __attribute__((ext_vector_type(4)));
typedef short bf16x8 __attribute__((ext_vector_type(8)));
typedef int   i32x4  __attribute__((ext_vector_type(4)));
typedef unsigned int u32x2 __attribute__((ext_vector_type(2)));

// ---- DPP helpers (epilogue red16 only) ----
template <int CTRL>
__device__ __forceinline__ float dppmov(float v) {
  return __int_as_float(__builtin_amdgcn_update_dpp(
      0, __float_as_int(v), CTRL, 0xF, 0xF, true));
}
template <int CTRL>
__device__ __forceinline__ float dpp_add(float v) { return v + dppmov<CTRL>(v); }
__device__ __forceinline__ float red16(float v) {
  v = dpp_add<0xB1>(v); v = dpp_add<0x4E>(v);
  v = dpp_add<0x141>(v); v = dpp_add<0x140>(v);
  return v;
}
__device__ __forceinline__ float sigmoid_fast(float z) {
  float e = __builtin_amdgcn_exp2f(z * -1.442695041f);
  return __builtin_amdgcn_rcpf(1.0f + e);
}
// v_cvt_pk_bf16_f32: two f32 -> one u32 of two bf16 (no builtin on gfx950)
__device__ __forceinline__ int cvt_pk_bf16(float a, float b) {
  int r; asm("v_cvt_pk_bf16_f32 %0, %1, %2" : "=v"(r) : "v"(a), "v"(b)); return r;
}
// split 8 f32 into hi/lo bf16 words (hi = bf16(v), lo = bf16(v - f32(hi)))
__device__ __forceinline__ void split8(const float* v, int* hw, int* lw) {
#pragma unroll
  for (int p = 0; p < 4; ++p) {
    int h = cvt_pk_bf16(v[2*p], v[2*p+1]);
    float f0 = __int_as_float(h << 16);
    float f1 = __int_as_float(h & 0xffff0000);
    lw[p] = cvt_pk_bf16(v[2*p] - f0, v[2*p+1] - f1);
    hw[p] = h;
  }
}
__device__ __forceinline__ bf16x8 frag4(const int* w) {
  return __builtin_bit_cast(bf16x8, (i32x4){w[0], w[1], w[2], w[3]});
}

// sum over the 4 q-lanes of a batch column (lanes c, c+16, c+32, c+48).
// R9: pure-VALU via gfx950 permlane swaps -- NO LDS ops / lgkmcnt on the
// per-step critical path (R7's ds_swizzle+ds_bpermute was ~240+ cyc of
// exposed latency per step at 1 wave/SIMD).
// Validated: R8's H output (which flows through this redq every step)
// passed bit-tolerance; the adds are commutative so the result is
// bitwise identical to the R7 LDS path.
__device__ __forceinline__ float redq(float v) {
#if __has_builtin(__builtin_amdgcn_permlane16_swap) && __has_builtin(__builtin_amdgcn_permlane32_swap)
  unsigned iv = __float_as_uint(v);
  u32x2 p = __builtin_amdgcn_permlane16_swap(iv, iv, false, false);
  float s = __uint_as_float(p[0]) + __uint_as_float(p[1]);
  unsigned is = __float_as_uint(s);
  u32x2 qq = __builtin_amdgcn_permlane32_swap(is, is, false, false);
  return __uint_as_float(qq[0]) + __uint_as_float(qq[1]);
#else
  v += __int_as_float(__builtin_amdgcn_ds_swizzle(__float_as_int(v), 0x401F));
  int l = (int)(threadIdx.x & 63);
  v += __int_as_float(__builtin_amdgcn_ds_bpermute(((l ^ 32) << 2),
                                                   __float_as_int(v)));
  return v;
#endif
}

// Time-chunked RNN scan with MFMA inner product.
// Lesson ledger: (R1) VGPR cap >= live set; (R4) plain f16/bf16 Wh.h is
// fatal -> split-bf16 3-product MFMA (z-err ~3e-6); (R5/R6) issue-bound
// regime: time ~ total wave-instrs; (R7) MFMA core verified @190us,
// latency-bound at 1 wave/SIMD; (R8) 8-chunk/512-thr restructure broke
// Output-1 (P path) while H passed -> REVERTED; permlane redq validated
// by R8's passing H. R9 = R7 + permlane redq ONLY (clean bisect).
//
// Wave layout: batch = lane&15 (16 batches/wave), q = lane>>4.
// Slot->unit map (shared by A and B so HW k-permutation cancels):
//   slot kk<4 -> unit 4q+kk ; kk>=4 -> unit 16+4q+(kk-4)
// D-layout: col=lane&15(batch), row=4q+reg / 16+4q+reg == same unit set
// -> sigmoid output feeds next step's B-operand entirely IN-LANE.
//
// Block = 256 thr = 4 chunk-waves x (same 16 batches). Chunks
// {16,280,528,776,1024}: 280 full steps each; chunks>=1: exact s1-only
// prescan from t=0 + 32-step h2 warm-up (contraction ~0.35/step, state
// err <1e-14; validated R2/R5/R6/R7).
__global__ __launch_bounds__(256) void mminet_fused(
    const float* __restrict__ x,   const float* __restrict__ var,
    const float* __restrict__ amps,const float* __restrict__ s0,
    const float* __restrict__ W1,  const float* __restrict__ b1,
    const float* __restrict__ Wx,  const float* __restrict__ Wh,
    const float* __restrict__ W2,  const float* __restrict__ b2,
    const float* __restrict__ Wm1, const float* __restrict__ bm1,
    const float* __restrict__ Wm2, const float* __restrict__ bm2,
    const float* __restrict__ Wm3, const float* __restrict__ bm3,
    float* __restrict__ Hout, float* __restrict__ out2)
{
  __shared__ float Pred[4][16];
  __shared__ float mlpbuf[16][64];

  const int tid   = threadIdx.x;
  const int l     = tid & 63;
  const int chunk = tid >> 6;                // wave id == chunk
  const int q     = l >> 4;                  // k-block / row-subblock
  const int c     = l & 15;                  // batch column
  const int b     = blockIdx.x * 16 + c;

  const int ob = (chunk == 0) ? SKIP : (chunk == 1) ? 280 : (chunk == 2) ? 528 : 776;
  const int oe = (chunk == 0) ? 280  : (chunk == 1) ? 528 : (chunk == 2) ? 776 : 1024;

  const float v0 = var[b*4+0], v1 = var[b*4+1], v2 = var[b*4+2], v3 = var[b*4+3];

  // ---- per-lane row constants for owned D-rows (== units) ----
  float wx0[8], wx1[8], wx2[8], cva[8], w1a[8], w2a[8], rc[8], s1[8];
#pragma unroll
  for (int i = 0; i < 8; ++i) {
    const int row = (i < 4) ? (4*q + i) : (16 + 4*q + (i - 4));
    if (row < HID) {
      wx0[i] = Wx[row*7+0]; wx1[i] = Wx[row*7+1]; wx2[i] = Wx[row*7+2];
      cva[i] = Wx[row*7+3]*v0 + Wx[row*7+4]*v1 + Wx[row*7+5]*v2 + Wx[row*7+6]*v3;
      w1a[i] = W1[row]; w2a[i] = W2[row];
      rc[i]  = 5.0f * (float)(row + 1) / 30.0f;
      s1[i]  = s0[b*HID + row];
    } else {
      wx0[i]=wx1[i]=wx2[i]=cva[i]=w1a[i]=w2a[i]=s1[i]=0.f; rc[i]=1.0f;
    }
  }

  // ---- A fragments (Wh, split-bf16), rows c and 16+c ----
  float a1v[8], a2v[8];
#pragma unroll
  for (int kk = 0; kk < 8; ++kk) {
    const int u = (kk < 4) ? (4*q + kk) : (16 + 4*q + (kk - 4));
    a1v[kk] = (u < HID) ? Wh[c*HID + u] : 0.f;
    a2v[kk] = (u < HID && (16 + c) < HID) ? Wh[(16+c)*HID + u] : 0.f;
  }
  int t0[4], t1[4], t2[4], t3[4];
  split8(a1v, t0, t1); split8(a2v, t2, t3);
  const bf16x8 A1h = frag4(t0), A1l = frag4(t1);
  const bf16x8 A2h = frag4(t2), A2l = frag4(t3);

  const float hcst = W1[30]*v0 + W1[31]*v1 + W1[32]*v2 + W1[33]*v3 + b1[0];
  const float hc2  = hcst + b2[0];

  float sw = 0.f;
#pragma unroll
  for (int i = 0; i < 8; ++i) sw += w2a[i];
  const float sumW2 = redq(sw);

  const float4* xb = (const float4*)(x + (size_t)b * S_LEN * 4);

  bf16x8 Bhi, Blo;
  auto packB = [&](const float* hv) {
    int bh[4], bl[4];
    split8(hv, bh, bl);
    Bhi = frag4(bh); Blo = frag4(bl);
  };

  // one RNN step for 16 batches: 6 MFMA + VALU epilogue
  auto dostep = [&](const float4 xq) -> float {
#pragma unroll
    for (int i = 0; i < 8; ++i)
      s1[i] = __builtin_amdgcn_fmed3f(s1[i] + xq.y, -rc[i], rc[i]);
    f32x4 z0, z1;
#pragma unroll
    for (int i = 0; i < 4; ++i) {
      z0[i] = cva[i]   + wx0[i]*xq.x   + wx1[i]*xq.z   + wx2[i]*xq.w;
      z1[i] = cva[i+4] + wx0[i+4]*xq.x + wx1[i+4]*xq.z + wx2[i+4]*xq.w;
    }
    z0 = __builtin_amdgcn_mfma_f32_16x16x32_bf16(A1h, Bhi, z0, 0, 0, 0);
    z0 = __builtin_amdgcn_mfma_f32_16x16x32_bf16(A1l, Bhi, z0, 0, 0, 0);
    z0 = __builtin_amdgcn_mfma_f32_16x16x32_bf16(A1h, Blo, z0, 0, 0, 0);
    z1 = __builtin_amdgcn_mfma_f32_16x16x32_bf16(A2h, Bhi, z1, 0, 0, 0);
    z1 = __builtin_amdgcn_mfma_f32_16x16x32_bf16(A2l, Bhi, z1, 0, 0, 0);
    z1 = __builtin_amdgcn_mfma_f32_16x16x32_bf16(A2h, Blo, z1, 0, 0, 0);
    float hv[8];
#pragma unroll
    for (int i = 0; i < 4; ++i) {
      hv[i]     = sigmoid_fast(z0[i]);
      hv[4 + i] = sigmoid_fast(z1[i]);
    }
    packB(hv);                                 // B for NEXT step, in-lane
    float hp = 0.f;
#pragma unroll
    for (int i = 0; i < 8; ++i)
      hp = fmaf(w1a[i], s1[i], fmaf(w2a[i], hv[i], hp));
    return redq(hp);                           // + hc2 by caller
  };

  float P = 0.f, Hprev = 0.f, Bprev = 0.f;
  float4 xc;

  if (chunk == 0) {
    // ---- t = 0 prologue (exact reference init) ----
    float4 xv = xb[0];
#pragma unroll
    for (int i = 0; i < 8; ++i)
      s1[i] = __builtin_amdgcn_fmed3f(s1[i] + xv.y, -rc[i], rc[i]);
    float hh = 0.f;
#pragma unroll
    for (int i = 0; i < 8; ++i) hh = fmaf(w1a[i], s1[i], hh);
    const float Hh0  = redq(hh) + hcst;
    const float hpre = (xv.x - Hh0) / sumW2;   // uniform initial h2
    float hv[8];
#pragma unroll
    for (int i = 0; i < 8; ++i) {
      const int row = (i < 4) ? (4*q + i) : (16 + 4*q + (i - 4));
      float rs = 0.f;
      if (row < HID)
        for (int u2 = 0; u2 < HID; ++u2) rs += Wh[row*HID + u2];
      float z = cva[i] + wx0[i]*xv.x + wx1[i]*xv.z + wx2[i]*xv.w + rs*hpre;
      hv[i] = sigmoid_fast(z);
    }
    packB(hv);
    // ---- t = 1..15 : recurrence only ----
    xc = xb[1];
    for (int t = 1; t < SKIP; ++t) {
      float4 xn = xb[t + 1];
      (void)dostep(xc);
      xc = xn;
    }                                          // xc == xb[ob]
  } else {
    // ---- s1-only exact prescan over [0, ob-WARM) ----
    const int ps = ob - WARM;                  // 248/496/744, %8==0
    const float* xf = x + (size_t)b * S_LEN * 4;
    for (int t = 0; t < ps; t += 8) {
      float d[8];
#pragma unroll
      for (int u = 0; u < 8; ++u) d[u] = xf[(t + u)*4 + 1];
#pragma unroll
      for (int u = 0; u < 8; ++u) {
#pragma unroll
        for (int i = 0; i < 8; ++i)
          s1[i] = __builtin_amdgcn_fmed3f(s1[i] + d[u], -rc[i], rc[i]);
      }
    }
    // ---- h2 warm-up over [ps, ob): 32 full steps from h=0.5 ----
    float hv[8];
#pragma unroll
    for (int i = 0; i < 8; ++i) hv[i] = 0.5f;
    packB(hv);
    float plast = 0.f;
    xc = xb[ps];
    for (int t = ps; t < ob; ++t) {
      float4 xn = xb[t + 1];
      plast = dostep(xc);
      Bprev = xc.x;
      xc = xn;
    }
    Hprev = plast + hc2;                       // xc == xb[ob]
  }

  // ---- output steps t = ob..oe-1 ----
  for (int t = ob; t < oe; t += 4) {
    float hq[4];
#pragma unroll
    for (int u = 0; u < 4; ++u) {
      int tn = t + u + 1; if (tn > oe - 1) tn = oe - 1;
      float4 xn = xb[tn];
      float Ht = dostep(xc) + hc2;
      if (t + u > SKIP) P += (xc.x - Bprev) * (Ht + Hprev);
      Hprev = Ht; Bprev = xc.x;
      hq[u] = Ht;
      xc = xn;
    }
    if (l < 16) {                              // q==0 lane stores batch c
      *(float4*)(Hout + (size_t)b * HLEN + (t - SKIP)) =
          make_float4(hq[0], hq[1], hq[2], hq[3]);
    }
  }

  // ---- cross-chunk trapezoid-sum reduction ----
  if (l < 16) Pred[chunk][c] = P;
  __syncthreads();

  // ==== fused MLP epilogue: 16 groups of 16 lanes, one batch each ====
  const int li = tid & 15;
  const int g  = tid >> 4;                     // 0..15
  const int be = blockIdx.x * 16 + g;
  const float Ptot = Pred[0][g] + Pred[1][g] + Pred[2][g] + Pred[3][g];
  const float e0 = var[be*4+0], e1 = var[be*4+1], e2 = var[be*4+2], e3 = var[be*4+3];
  const float am0 = amps[be*2+0], am1 = amps[be*2+1];

  float Pp = Ptot * 0.5f * am0 * am1;
  Pp *= __builtin_amdgcn_exp2f(e0 * 3.321928095f);     // * 10^var0
  Pp = fmaxf(Pp, 1e-12f);
  const float Pcv = __builtin_amdgcn_logf(Pp) * 0.30102999566f;  // log10

  float* hs = &mlpbuf[g][0];
#pragma unroll
  for (int qq = 0; qq < 4; ++qq) {
    const int n = li + 16 * qq;
    const float* wr = Wm1 + n * 5;
    float h1v = bm1[n] + wr[0]*e0 + wr[1]*e1 + wr[2]*e2 + wr[3]*e3 + wr[4]*Pcv;
    hs[n] = fmaxf(h1v, 0.f);                   // wave-synchronous in group
  }
  const int m0 = li, m1 = li + 16;
  const float4* h1v4 = (const float4*)hs;
  const float4* w2a4 = (const float4*)(Wm2 + m0 * 64);
  const float4* w2b4 = (const float4*)(Wm2 + m1 * 64);
  float zz0 = bm2[m0], zz1 = bm2[m1];
#pragma unroll
  for (int qq = 0; qq < 16; ++qq) {
    float4 hh = h1v4[qq];
    float4 wa = w2a4[qq], wb = w2b4[qq];
    zz0 += wa.x*hh.x + wa.y*hh.y + wa.z*hh.z + wa.w*hh.w;
    zz1 += wb.x*hh.x + wb.y*hh.y + wb.z*hh.z + wb.w*hh.w;
  }
  float sp = Wm3[m0] * fmaxf(zz0, 0.f) + Wm3[m1] * fmaxf(zz1, 0.f);
  sp = red16(sp);
  if (li == 0) out2[be] = Pcv + sp + bm3[0];
}

extern "C" void kernel_launch(void* const* d_in, const int* in_sizes, int n_in,
                              void* d_out, int out_size, void* d_ws, size_t ws_size,
                              hipStream_t stream)
{
  const float* x    = (const float*)d_in[0];
  const float* var  = (const float*)d_in[1];
  const float* amps = (const float*)d_in[2];
  const float* s0   = (const float*)d_in[3];
  const float* W1   = (const float*)d_in[4];
  const float* b1   = (const float*)d_in[5];
  const float* Wx   = (const float*)d_in[6];
  const float* Wh   = (const float*)d_in[7];
  const float* W2   = (const float*)d_in[8];
  const float* b2   = (const float*)d_in[9];
  const float* Wm1  = (const float*)d_in[10];
  const float* bm1  = (const float*)d_in[11];
  const float* Wm2  = (const float*)d_in[12];
  const float* bm2  = (const float*)d_in[13];
  const float* Wm3  = (const float*)d_in[14];
  const float* bm3  = (const float*)d_in[15];
  // d_in[16] = n_init (compile-time 16)

  float* Hout = (float*)d_out;
  float* out2 = (float*)d_out + (size_t)B_TOT * HLEN;

  mminet_fused<<<B_TOT / 16, 256, 0, stream>>>(
      x, var, amps, s0, W1, b1, Wx, Wh, W2, b2,
      Wm1, bm1, Wm2, bm2, Wm3, bm3, Hout, out2);
}

// Round 10
// 273.908 us; speedup vs baseline: 1.0609x; 1.0609x over previous
//
#include <hip/hip_runtime.h>

#define B_TOT 4096
#define S_LEN 1024
#define HID 30
#define SKIP 16
#define HLEN (S_LEN - SKIP)   // 1008
#define WARM 32               // min h2 warm-up steps for chunks >= 1

typedef float f32x4 __attribute__((ext_vector_type(4)));
typedef short bf16x8 __attribute__((ext_vector_type(8)));
typedef int   i32x4  __attribute__((ext_vector_type(4)));
typedef unsigned int u32x2 __attribute__((ext_vector_type(2)));

// ---- DPP helpers (epilogue red16 only) ----
template <int CTRL>
__device__ __forceinline__ float dppmov(float v) {
  return __int_as_float(__builtin_amdgcn_update_dpp(
      0, __float_as_int(v), CTRL, 0xF, 0xF, true));
}
template <int CTRL>
__device__ __forceinline__ float dpp_add(float v) { return v + dppmov<CTRL>(v); }
__device__ __forceinline__ float red16(float v) {
  v = dpp_add<0xB1>(v); v = dpp_add<0x4E>(v);
  v = dpp_add<0x141>(v); v = dpp_add<0x140>(v);
  return v;
}
__device__ __forceinline__ float sigmoid_fast(float z) {
  float e = __builtin_amdgcn_exp2f(z * -1.442695041f);
  return __builtin_amdgcn_rcpf(1.0f + e);
}
// v_cvt_pk_bf16_f32: two f32 -> one u32 of two bf16 (no builtin on gfx950)
__device__ __forceinline__ int cvt_pk_bf16(float a, float b) {
  int r; asm("v_cvt_pk_bf16_f32 %0, %1, %2" : "=v"(r) : "v"(a), "v"(b)); return r;
}
// split 8 f32 into hi/lo bf16 words (hi = bf16(v), lo = bf16(v - f32(hi)))
__device__ __forceinline__ void split8(const float* v, int* hw, int* lw) {
#pragma unroll
  for (int p = 0; p < 4; ++p) {
    int h = cvt_pk_bf16(v[2*p], v[2*p+1]);
    float f0 = __int_as_float(h << 16);
    float f1 = __int_as_float(h & 0xffff0000);
    lw[p] = cvt_pk_bf16(v[2*p] - f0, v[2*p+1] - f1);
    hw[p] = h;
  }
}
__device__ __forceinline__ bf16x8 frag4(const int* w) {
  return __builtin_bit_cast(bf16x8, (i32x4){w[0], w[1], w[2], w[3]});
}

// sum over the 4 q-lanes of a batch column -- pure-VALU permlane swaps
// (validated R8/R9: H output flows through this every step and passed).
__device__ __forceinline__ float redq(float v) {
#if __has_builtin(__builtin_amdgcn_permlane16_swap) && __has_builtin(__builtin_amdgcn_permlane32_swap)
  unsigned iv = __float_as_uint(v);
  u32x2 p = __builtin_amdgcn_permlane16_swap(iv, iv, false, false);
  float s = __uint_as_float(p[0]) + __uint_as_float(p[1]);
  unsigned is = __float_as_uint(s);
  u32x2 qq = __builtin_amdgcn_permlane32_swap(is, is, false, false);
  return __uint_as_float(qq[0]) + __uint_as_float(qq[1]);
#else
  v += __int_as_float(__builtin_amdgcn_ds_swizzle(__float_as_int(v), 0x401F));
  int l = (int)(threadIdx.x & 63);
  v += __int_as_float(__builtin_amdgcn_ds_bpermute(((l ^ 32) << 2),
                                                   __float_as_int(v)));
  return v;
#endif
}

// Time-chunked RNN scan with MFMA inner product.
// Lesson ledger: (R1) VGPR cap >= live set; (R4) plain f16/bf16 Wh.h fatal
// -> split-bf16 3-product MFMA; (R5/R6) issue-bound: minimize wave-instrs;
// (R7) MFMA core verified @190us; (R8) 8-chunk restructure broke P ->
// reverted; (R9) permlane redq = 0 gain -> redq is OFF the loop-carried
// chain; remaining ~1000cyc/step gap attributed to per-step x-load latency
// waited at step end (1-ahead prefetch too shallow for L3/HBM ~400-900cyc).
// R10: (a) 4-deep x prefetch via unified 4-block warm+output loop,
// (b) prescan 32-value double-buffered pipeline, (c) independent MFMA
// accumulators (3 serial -> 3 parallel + adds).
//
// Wave layout: batch = lane&15 (16 batches/wave), q = lane>>4.
// Slot->unit map (shared by A and B so HW k-permutation cancels):
//   slot kk<4 -> unit 4q+kk ; kk>=4 -> unit 16+4q+(kk-4)
// D-layout: col=lane&15(batch), row=4q+reg / 16+4q+reg == same unit set
// -> sigmoid output feeds next step's B-operand entirely IN-LANE.
//
// Block = 256 thr = 4 chunk-waves x (same 16 batches). Chunks
// {16,280,528,776,1024}. Chunks>=1: exact s1-only prescan [0,ps),
// ps=(ob-32)&~31, then 40-56 full warm-up steps (contraction ~0.35/step,
// state err <1e-14; validated R2/R5/R6/R7/R9).
__global__ __launch_bounds__(256) void mminet_fused(
    const float* __restrict__ x,   const float* __restrict__ var,
    const float* __restrict__ amps,const float* __restrict__ s0,
    const float* __restrict__ W1,  const float* __restrict__ b1,
    const float* __restrict__ Wx,  const float* __restrict__ Wh,
    const float* __restrict__ W2,  const float* __restrict__ b2,
    const float* __restrict__ Wm1, const float* __restrict__ bm1,
    const float* __restrict__ Wm2, const float* __restrict__ bm2,
    const float* __restrict__ Wm3, const float* __restrict__ bm3,
    float* __restrict__ Hout, float* __restrict__ out2)
{
  __shared__ float Pred[4][16];
  __shared__ float mlpbuf[16][64];

  const int tid   = threadIdx.x;
  const int l     = tid & 63;
  const int chunk = tid >> 6;                // wave id == chunk
  const int q     = l >> 4;                  // k-block / row-subblock
  const int c     = l & 15;                  // batch column
  const int b     = blockIdx.x * 16 + c;

  const int ob = (chunk == 0) ? SKIP : (chunk == 1) ? 280 : (chunk == 2) ? 528 : 776;
  const int oe = (chunk == 0) ? 280  : (chunk == 1) ? 528 : (chunk == 2) ? 776 : 1024;
  // unified-loop start: chunk0 = SKIP; else 32-aligned prescan end
  const int ps = (chunk == 0) ? SKIP : ((ob - WARM) & ~31);  // 224/480/736

  const float v0 = var[b*4+0], v1 = var[b*4+1], v2 = var[b*4+2], v3 = var[b*4+3];

  // ---- per-lane row constants for owned D-rows (== units) ----
  float wx0[8], wx1[8], wx2[8], cva[8], w1a[8], w2a[8], rc[8], s1[8];
#pragma unroll
  for (int i = 0; i < 8; ++i) {
    const int row = (i < 4) ? (4*q + i) : (16 + 4*q + (i - 4));
    if (row < HID) {
      wx0[i] = Wx[row*7+0]; wx1[i] = Wx[row*7+1]; wx2[i] = Wx[row*7+2];
      cva[i] = Wx[row*7+3]*v0 + Wx[row*7+4]*v1 + Wx[row*7+5]*v2 + Wx[row*7+6]*v3;
      w1a[i] = W1[row]; w2a[i] = W2[row];
      rc[i]  = 5.0f * (float)(row + 1) / 30.0f;
      s1[i]  = s0[b*HID + row];
    } else {
      wx0[i]=wx1[i]=wx2[i]=cva[i]=w1a[i]=w2a[i]=s1[i]=0.f; rc[i]=1.0f;
    }
  }

  // ---- A fragments (Wh, split-bf16), rows c and 16+c ----
  float a1v[8], a2v[8];
#pragma unroll
  for (int kk = 0; kk < 8; ++kk) {
    const int u = (kk < 4) ? (4*q + kk) : (16 + 4*q + (kk - 4));
    a1v[kk] = (u < HID) ? Wh[c*HID + u] : 0.f;
    a2v[kk] = (u < HID && (16 + c) < HID) ? Wh[(16+c)*HID + u] : 0.f;
  }
  int t0[4], t1[4], t2[4], t3[4];
  split8(a1v, t0, t1); split8(a2v, t2, t3);
  const bf16x8 A1h = frag4(t0), A1l = frag4(t1);
  const bf16x8 A2h = frag4(t2), A2l = frag4(t3);

  const float hcst = W1[30]*v0 + W1[31]*v1 + W1[32]*v2 + W1[33]*v3 + b1[0];
  const float hc2  = hcst + b2[0];

  float sw = 0.f;
#pragma unroll
  for (int i = 0; i < 8; ++i) sw += w2a[i];
  const float sumW2 = redq(sw);

  const float4* xb = (const float4*)(x + (size_t)b * S_LEN * 4);

  bf16x8 Bhi, Blo;
  auto packB = [&](const float* hv) {
    int bh[4], bl[4];
    split8(hv, bh, bl);
    Bhi = frag4(bh); Blo = frag4(bl);
  };

  // one RNN step for 16 batches: 6 independent MFMA + VALU epilogue
  auto dostep = [&](const float4 xq) -> float {
#pragma unroll
    for (int i = 0; i < 8; ++i)
      s1[i] = __builtin_amdgcn_fmed3f(s1[i] + xq.y, -rc[i], rc[i]);
    f32x4 zi0, zi1;
#pragma unroll
    for (int i = 0; i < 4; ++i) {
      zi0[i] = cva[i]   + wx0[i]*xq.x   + wx1[i]*xq.z   + wx2[i]*xq.w;
      zi1[i] = cva[i+4] + wx0[i+4]*xq.x + wx1[i+4]*xq.z + wx2[i+4]*xq.w;
    }
    const f32x4 zz = {0.f, 0.f, 0.f, 0.f};
    // independent accumulators: 3 MFMAs issue back-to-back (latency
    // overlapped), summed after -- shortens the loop-carried chain
    f32x4 a0 = __builtin_amdgcn_mfma_f32_16x16x32_bf16(A1h, Bhi, zi0, 0, 0, 0);
    f32x4 b0 = __builtin_amdgcn_mfma_f32_16x16x32_bf16(A1l, Bhi, zz,  0, 0, 0);
    f32x4 c0 = __builtin_amdgcn_mfma_f32_16x16x32_bf16(A1h, Blo, zz,  0, 0, 0);
    f32x4 a1 = __builtin_amdgcn_mfma_f32_16x16x32_bf16(A2h, Bhi, zi1, 0, 0, 0);
    f32x4 b1v= __builtin_amdgcn_mfma_f32_16x16x32_bf16(A2l, Bhi, zz,  0, 0, 0);
    f32x4 c1 = __builtin_amdgcn_mfma_f32_16x16x32_bf16(A2h, Blo, zz,  0, 0, 0);
    f32x4 z0 = (a0 + b0) + c0;
    f32x4 z1 = (a1 + b1v) + c1;
    float hv[8];
#pragma unroll
    for (int i = 0; i < 4; ++i) {
      hv[i]     = sigmoid_fast(z0[i]);
      hv[4 + i] = sigmoid_fast(z1[i]);
    }
    packB(hv);                                 // B for NEXT step, in-lane
    float hp = 0.f;
#pragma unroll
    for (int i = 0; i < 8; ++i)
      hp = fmaf(w1a[i], s1[i], fmaf(w2a[i], hv[i], hp));
    return redq(hp);                           // + hc2 by caller
  };

  if (chunk == 0) {
    // ---- t = 0 prologue (exact reference init) ----
    float4 xv = xb[0];
#pragma unroll
    for (int i = 0; i < 8; ++i)
      s1[i] = __builtin_amdgcn_fmed3f(s1[i] + xv.y, -rc[i], rc[i]);
    float hh = 0.f;
#pragma unroll
    for (int i = 0; i < 8; ++i) hh = fmaf(w1a[i], s1[i], hh);
    const float Hh0  = redq(hh) + hcst;
    const float hpre = (xv.x - Hh0) / sumW2;   // uniform initial h2
    float hv[8];
#pragma unroll
    for (int i = 0; i < 8; ++i) {
      const int row = (i < 4) ? (4*q + i) : (16 + 4*q + (i - 4));
      float rs = 0.f;
      if (row < HID)
        for (int u2 = 0; u2 < HID; ++u2) rs += Wh[row*HID + u2];
      float z = cva[i] + wx0[i]*xv.x + wx1[i]*xv.z + wx2[i]*xv.w + rs*hpre;
      hv[i] = sigmoid_fast(z);
    }
    packB(hv);
    // ---- t = 1..15 : recurrence only (15 steps, once per kernel) ----
    for (int t = 1; t < SKIP; ++t) (void)dostep(xb[t]);
  } else {
    // ---- s1-only exact prescan over [0, ps): 32-deep pipelined ----
    const float* xf = x + (size_t)b * S_LEN * 4;
    float dc[32], dn[32];
#pragma unroll
    for (int u = 0; u < 32; ++u) dc[u] = xf[u*4 + 1];
    for (int t = 0; t < ps; t += 32) {
      const bool more = (t + 32 < ps);          // wave-uniform
      if (more) {
#pragma unroll
        for (int u = 0; u < 32; ++u) dn[u] = xf[(t + 32 + u)*4 + 1];
      }
#pragma unroll
      for (int u = 0; u < 32; ++u) {
#pragma unroll
        for (int i = 0; i < 8; ++i)
          s1[i] = __builtin_amdgcn_fmed3f(s1[i] + dc[u], -rc[i], rc[i]);
      }
      if (more) {
#pragma unroll
        for (int u = 0; u < 32; ++u) dc[u] = dn[u];
      }
    }
    // h2 warm-up handled by the unified loop below (t in [ps, ob))
    float hv[8];
#pragma unroll
    for (int i = 0; i < 8; ++i) hv[i] = 0.5f;
    packB(hv);
  }

  // ==== unified warm+output loop: t in [ps, oe), 4-block, 4-deep
  // prefetch. Blocks align with ob (ps,ob both %4==0). P pairs only for
  // s >= ob (chunks>=1: warm region excluded; boundary pair (ob-1,ob)
  // uses Hprev/Bprev set by the last warm step) and s > SKIP (chunk 0's
  // first output). Stores only when t >= ob (block-uniform).
  float P = 0.f, Hprev = 0.f, Bprev = 0.f;
  float4 xc0 = xb[ps+0], xc1 = xb[ps+1], xc2 = xb[ps+2], xc3 = xb[ps+3];

  for (int t = ps; t < oe; t += 4) {
    const int tn = (t + 4 < oe) ? (t + 4) : t;  // uniform
    float4 xn0 = xb[tn+0], xn1 = xb[tn+1], xn2 = xb[tn+2], xn3 = xb[tn+3];

    float hq0, hq1, hq2, hq3;
    {
      float Ht = dostep(xc0) + hc2;
      if (t + 0 > SKIP && t + 0 >= ob) P += (xc0.x - Bprev) * (Ht + Hprev);
      Hprev = Ht; Bprev = xc0.x; hq0 = Ht;
    }
    {
      float Ht = dostep(xc1) + hc2;
      if (t + 1 > SKIP && t + 1 >= ob) P += (xc1.x - Bprev) * (Ht + Hprev);
      Hprev = Ht; Bprev = xc1.x; hq1 = Ht;
    }
    {
      float Ht = dostep(xc2) + hc2;
      if (t + 2 > SKIP && t + 2 >= ob) P += (xc2.x - Bprev) * (Ht + Hprev);
      Hprev = Ht; Bprev = xc2.x; hq2 = Ht;
    }
    {
      float Ht = dostep(xc3) + hc2;
      if (t + 3 > SKIP && t + 3 >= ob) P += (xc3.x - Bprev) * (Ht + Hprev);
      Hprev = Ht; Bprev = xc3.x; hq3 = Ht;
    }
    if (t >= ob && l < 16) {                   // q==0 lane stores batch c
      *(float4*)(Hout + (size_t)b * HLEN + (t - SKIP)) =
          make_float4(hq0, hq1, hq2, hq3);
    }
    xc0 = xn0; xc1 = xn1; xc2 = xn2; xc3 = xn3;
  }

  // ---- cross-chunk trapezoid-sum reduction ----
  if (l < 16) Pred[chunk][c] = P;
  __syncthreads();

  // ==== fused MLP epilogue: 16 groups of 16 lanes, one batch each ====
  const int li = tid & 15;
  const int g  = tid >> 4;                     // 0..15
  const int be = blockIdx.x * 16 + g;
  const float Ptot = Pred[0][g] + Pred[1][g] + Pred[2][g] + Pred[3][g];
  const float e0 = var[be*4+0], e1 = var[be*4+1], e2 = var[be*4+2], e3 = var[be*4+3];
  const float am0 = amps[be*2+0], am1 = amps[be*2+1];

  float Pp = Ptot * 0.5f * am0 * am1;
  Pp *= __builtin_amdgcn_exp2f(e0 * 3.321928095f);     // * 10^var0
  Pp = fmaxf(Pp, 1e-12f);
  const float Pcv = __builtin_amdgcn_logf(Pp) * 0.30102999566f;  // log10

  float* hs = &mlpbuf[g][0];
#pragma unroll
  for (int qq = 0; qq < 4; ++qq) {
    const int n = li + 16 * qq;
    const float* wr = Wm1 + n * 5;
    float h1v = bm1[n] + wr[0]*e0 + wr[1]*e1 + wr[2]*e2 + wr[3]*e3 + wr[4]*Pcv;
    hs[n] = fmaxf(h1v, 0.f);                   // wave-synchronous in group
  }
  const int m0 = li, m1 = li + 16;
  const float4* h1v4 = (const float4*)hs;
  const float4* w2a4 = (const float4*)(Wm2 + m0 * 64);
  const float4* w2b4 = (const float4*)(Wm2 + m1 * 64);
  float zz0 = bm2[m0], zz1 = bm2[m1];
#pragma unroll
  for (int qq = 0; qq < 16; ++qq) {
    float4 hh = h1v4[qq];
    float4 wa = w2a4[qq], wb = w2b4[qq];
    zz0 += wa.x*hh.x + wa.y*hh.y + wa.z*hh.z + wa.w*hh.w;
    zz1 += wb.x*hh.x + wb.y*hh.y + wb.z*hh.z + wb.w*hh.w;
  }
  float sp = Wm3[m0] * fmaxf(zz0, 0.f) + Wm3[m1] * fmaxf(zz1, 0.f);
  sp = red16(sp);
  if (li == 0) out2[be] = Pcv + sp + bm3[0];
}

extern "C" void kernel_launch(void* const* d_in, const int* in_sizes, int n_in,
                              void* d_out, int out_size, void* d_ws, size_t ws_size,
                              hipStream_t stream)
{
  const float* x    = (const float*)d_in[0];
  const float* var  = (const float*)d_in[1];
  const float* amps = (const float*)d_in[2];
  const float* s0   = (const float*)d_in[3];
  const float* W1   = (const float*)d_in[4];
  const float* b1   = (const float*)d_in[5];
  const float* Wx   = (const float*)d_in[6];
  const float* Wh   = (const float*)d_in[7];
  const float* W2   = (const float*)d_in[8];
  const float* b2   = (const float*)d_in[9];
  const float* Wm1  = (const float*)d_in[10];
  const float* bm1  = (const float*)d_in[11];
  const float* Wm2  = (const float*)d_in[12];
  const float* bm2  = (const float*)d_in[13];
  const float* Wm3  = (const float*)d_in[14];
  const float* bm3  = (const float*)d_in[15];
  // d_in[16] = n_init (compile-time 16)

  float* Hout = (float*)d_out;
  float* out2 = (float*)d_out + (size_t)B_TOT * HLEN;

  mminet_fused<<<B_TOT / 16, 256, 0, stream>>>(
      x, var, amps, s0, W1, b1, Wx, Wh, W2, b2,
      Wm1, bm1, Wm2, bm2, Wm3, bm3, Hout, out2);
}